// Round 15
// baseline (462.040 us; speedup 1.0000x reference)
//
#include <hip/hip_runtime.h>
#include <stdint.h>

#define D 128
#define CB_SHIFT 10     // coarse bucket = 1024 dst nodes
#define CB_NODES 1024
#define CHE 2048        // edges per multisplit chunk (2*CHE entries)
#define NBC_MAX 512

typedef __attribute__((ext_vector_type(8))) short bf16x8_t;
typedef __attribute__((ext_vector_type(4))) float f32x4_t;
typedef __attribute__((ext_vector_type(4))) unsigned uint4v;

__device__ inline unsigned short f2bf(float x) {
    unsigned int u = __float_as_uint(x);
    unsigned int r = (u + 0x7fffu + ((u >> 16) & 1u)) >> 16;   // RNE
    return (unsigned short)r;
}
__device__ inline float bflo(unsigned v) { return __uint_as_float(v << 16); }

// ---------------------------------------------------------------------------
// f32 -> bf16 bulk convert, both arrays in one launch
// ---------------------------------------------------------------------------
__global__ __launch_bounds__(256) void f32_to_bf16_duo(
        const float* __restrict__ inA, unsigned short* __restrict__ outA, int n8A,
        const float* __restrict__ inP, unsigned short* __restrict__ outP, int n8P) {
    int stride = gridDim.x * blockDim.x;
    int total = n8A + n8P;
    for (int i = blockIdx.x * blockDim.x + threadIdx.x; i < total; i += stride) {
        const float* in; unsigned short* out; int j;
        if (i < n8A) { in = inA; out = outA; j = i; }
        else         { in = inP; out = outP; j = i - n8A; }
        float4 v0 = *(const float4*)(in + (size_t)j * 8);
        float4 v1 = *(const float4*)(in + (size_t)j * 8 + 4);
        uint4 o;
        o.x = f2bf(v0.x) | ((unsigned)f2bf(v0.y) << 16);
        o.y = f2bf(v0.z) | ((unsigned)f2bf(v0.w) << 16);
        o.z = f2bf(v1.x) | ((unsigned)f2bf(v1.y) << 16);
        o.w = f2bf(v1.z) | ((unsigned)f2bf(v1.w) << 16);
        *(uint4*)(out + (size_t)j * 8) = o;
    }
}

// ---------------------------------------------------------------------------
// coarse bucket histogram
// ---------------------------------------------------------------------------
__global__ __launch_bounds__(256) void coarse_count_kernel(
        const int* __restrict__ ea, const int* __restrict__ ep, int E,
        int nbcA, int nbc, int* __restrict__ chist) {
    __shared__ int hist[NBC_MAX];
    int tid = threadIdx.x;
    for (int i = tid; i < NBC_MAX; i += 256) hist[i] = 0;
    __syncthreads();
    int e0 = blockIdx.x * CHE;
    int ecnt = E - e0; if (ecnt > CHE) ecnt = CHE;
    for (int k = tid; k < ecnt; k += 256) {
        int a = ea[e0 + k], p = ep[e0 + k];
        atomicAdd(&hist[a >> CB_SHIFT], 1);
        atomicAdd(&hist[nbcA + (p >> CB_SHIFT)], 1);
    }
    __syncthreads();
    for (int i = tid; i < nbc; i += 256)
        if (hist[i]) atomicAdd(&chist[i], hist[i]);
}

// ---------------------------------------------------------------------------
// tiny segmented scan of the coarse counts (1 block)
// ---------------------------------------------------------------------------
__global__ __launch_bounds__(NBC_MAX) void coarse_scan_kernel(
        const int* __restrict__ chist, int nbcA, int nbc, int E,
        int* __restrict__ gcur, int* __restrict__ cbase,
        int* __restrict__ rsA_end, int* __restrict__ rsP_end) {
    __shared__ int s[NBC_MAX];
    int tid = threadIdx.x;
    int v = (tid < nbc) ? chist[tid] : 0;
    s[tid] = v;
    __syncthreads();
    for (int off = 1; off < NBC_MAX; off <<= 1) {
        int add = 0;
        if (tid >= off && ((tid < nbcA) || (tid - off >= nbcA))) add = s[tid - off];
        __syncthreads();
        s[tid] += add;
        __syncthreads();
    }
    int excl = s[tid] - v;
    if (tid < nbc) {
        cbase[tid] = excl;
        gcur[tid] = (tid < nbcA) ? excl : E + excl;
    }
    if (tid == 0) { *rsA_end = E; *rsP_end = E; }
}

// ---------------------------------------------------------------------------
// LDS multisplit (block-owned contiguous runs per coarse bucket), 512 thr
// ---------------------------------------------------------------------------
__global__ __launch_bounds__(512) void multisplit_kernel(
        const int* __restrict__ ea, const int* __restrict__ ep, int E,
        int nbcA, int* __restrict__ gcur, unsigned* __restrict__ buf) {
    __shared__ int hist[NBC_MAX];
    __shared__ int off[NBC_MAX];
    __shared__ int cnt2[NBC_MAX];
    __shared__ int gbase[NBC_MAX];
    __shared__ unsigned cbuf[2 * CHE];          // 16 KB
    __shared__ unsigned short bkt[2 * CHE];     // 8 KB

    int tid = threadIdx.x;
    int e0 = blockIdx.x * CHE;
    int ecnt = E - e0; if (ecnt > CHE) ecnt = CHE;

    hist[tid] = 0;
    __syncthreads();

    for (int k = tid; k < ecnt; k += 512) {
        int a = ea[e0 + k], p = ep[e0 + k];
        atomicAdd(&hist[a >> CB_SHIFT], 1);
        atomicAdd(&hist[nbcA + (p >> CB_SHIFT)], 1);
    }
    __syncthreads();

    int v = hist[tid];
    off[tid] = v;
    __syncthreads();
    for (int o = 1; o < NBC_MAX; o <<= 1) {
        int y = (tid >= o) ? off[tid - o] : 0;
        __syncthreads();
        off[tid] += y;
        __syncthreads();
    }
    int excl = off[tid] - v;
    off[tid] = excl;
    cnt2[tid] = 0;
    if (v > 0) gbase[tid] = atomicAdd(&gcur[tid], v);
    __syncthreads();

    for (int k = tid; k < ecnt; k += 512) {
        int a = ea[e0 + k], p = ep[e0 + k];
        int bA = a >> CB_SHIFT;
        int iA = off[bA] + atomicAdd(&cnt2[bA], 1);
        cbuf[iA] = ((unsigned)p << CB_SHIFT) | (unsigned)(a & (CB_NODES - 1));
        bkt[iA] = (unsigned short)bA;
        int bP = nbcA + (p >> CB_SHIFT);
        int iP = off[bP] + atomicAdd(&cnt2[bP], 1);
        cbuf[iP] = ((unsigned)a << CB_SHIFT) | (unsigned)(p & (CB_NODES - 1));
        bkt[iP] = (unsigned short)bP;
    }
    __syncthreads();

    int total = 2 * ecnt;
    for (int i = tid; i < total; i += 512) {
        int b = bkt[i];
        buf[(size_t)gbase[b] + (i - off[b])] = cbuf[i];
    }
}

// ---------------------------------------------------------------------------
// fine sort + LOCAL deg/rs derivation: one block per coarse bucket.
// ---------------------------------------------------------------------------
__global__ __launch_bounds__(1024) void fine_csr_kernel(
        const unsigned* __restrict__ buf, int E, int nbcA,
        const int* __restrict__ cbase, const int* __restrict__ chist,
        int* __restrict__ rsA, int* __restrict__ degA, int* __restrict__ csrA, int nA,
        int* __restrict__ rsP, int* __restrict__ degP, int* __restrict__ csrP, int nP) {
    __shared__ int cnt[CB_NODES];
    __shared__ int s[CB_NODES];
    __shared__ int pos[CB_NODES];
    int b = blockIdx.x;
    int tid = threadIdx.x;
    int isA = (b < nbcA);
    int d0 = (isA ? b : b - nbcA) << CB_SHIFT;
    int n  = isA ? nA : nP;
    int* rs  = isA ? rsA  : rsP;
    int* deg = isA ? degA : degP;
    int* csr = isA ? csrA : csrP;
    int cb   = cbase[b];
    int cntE = chist[b];
    size_t bstart = (isA ? (size_t)0 : (size_t)E) + (size_t)cb;

    cnt[tid] = 0;
    __syncthreads();
    for (int j = tid; j < cntE; j += 1024)
        atomicAdd(&cnt[buf[bstart + j] & (CB_NODES - 1)], 1);
    __syncthreads();

    int v = cnt[tid];
    s[tid] = v;
    __syncthreads();
    for (int o = 1; o < CB_NODES; o <<= 1) {
        int y = (tid >= o) ? s[tid - o] : 0;
        __syncthreads();
        s[tid] += y;
        __syncthreads();
    }
    int excl = s[tid] - v;
    int d = d0 + tid;
    if (d < n) { rs[d] = cb + excl; deg[d] = v; }

    pos[tid] = 0;
    cnt[tid] = excl;   // repurpose: per-dst exclusive base
    __syncthreads();

    for (int j = tid; j < cntE; j += 1024) {
        unsigned pk = buf[bstart + j];
        int li = pk & (CB_NODES - 1);
        int src = (int)(pk >> CB_SHIFT);
        int p = cb + cnt[li] + atomicAdd(&pos[li], 1);
        csr[p] = src;
    }
}

// ---------------------------------------------------------------------------
// W pre-pack (unchanged)
// ---------------------------------------------------------------------------
__global__ __launch_bounds__(256) void pack_w_kernel(
        const float* __restrict__ WsA, const float* __restrict__ WsP,
        const float* __restrict__ Wa2p, const float* __restrict__ Wp2a,
        unsigned short* __restrict__ Bpack) {
    int combo = blockIdx.x >> 4;
    int e = (blockIdx.x & 15) * 256 + threadIdx.x;   // 0..4095
    int layer = combo >> 1;
    const float* Ws = ((combo & 1) ? WsP : WsA) + (size_t)layer * D * D;
    const float* Wm = ((combo & 1) ? Wa2p : Wp2a) + (size_t)layer * D * D;

    int f = e >> 6, lane = e & 63;
    int nf = f >> 3, ks = f & 7;
    int k0 = ks * 32 + (lane >> 4) * 8;
    int col = nf * 16 + (lane & 15);

    unsigned short v[8];
#pragma unroll
    for (int j = 0; j < 8; ++j) {
        int k = k0 + j;
        float x = (k < D) ? Ws[(size_t)k * D + col] : Wm[(size_t)(k - D) * D + col];
        v[j] = f2bf(x);
    }
    uint4 o;
    o.x = v[0] | ((unsigned)v[1] << 16);
    o.y = v[2] | ((unsigned)v[3] << 16);
    o.z = v[4] | ((unsigned)v[5] << 16);
    o.w = v[6] | ((unsigned)v[7] << 16);
    *(uint4*)(Bpack + (size_t)combo * 32768 + (size_t)e * 8) = o;
}

// ---------------------------------------------------------------------------
// bf16 pull-aggregation: one wave per dst row, 4x16-lane subwaves, 16B/lane,
// dual-chain unroll with direct csr loads (round-14 passing config).
// NEW (single variable): agg output via NON-TEMPORAL stores — the 75MB
// streaming write was evicting the gather tables from L3 (FETCH 149MB vs
// 77MB compulsory). Tables are the reuse-heavy data; agg is consumed
// streaming-once by the linear (which has HBM headroom).
// ---------------------------------------------------------------------------
__global__ __launch_bounds__(256) void aggregate_duo(
        const unsigned short* __restrict__ srcA, const int* __restrict__ rsA,
        const int* __restrict__ csrA, int nA, unsigned short* __restrict__ aggA,
        const unsigned short* __restrict__ srcP, const int* __restrict__ rsP,
        const int* __restrict__ csrP, int nP, unsigned short* __restrict__ aggP) {
    int gw   = (blockIdx.x * 256 + threadIdx.x) >> 6;
    int lane = threadIdx.x & 63;
    int sub  = lane >> 4;
    int sl   = lane & 15;

    const unsigned short* xsrc; const int* rs; const int* csr;
    unsigned short* agg; int d;
    if (gw < nA) { d = gw;      xsrc = srcA; rs = rsA; csr = csrA; agg = aggA; }
    else {
        d = gw - nA;
        if (d >= nP) return;
        xsrc = srcP; rs = rsP; csr = csrP; agg = aggP;
    }

    int s0 = rs[d], s1 = rs[d + 1];
    float acc[8] = {0.f, 0.f, 0.f, 0.f, 0.f, 0.f, 0.f, 0.f};
    int j = s0 + sub;
    for (; j + 4 < s1; j += 8) {
        int sa = csr[j];
        int sb = csr[j + 4];
        uint4 va = *(const uint4*)((const char*)xsrc + ((size_t)sa << 8) + sl * 16);
        uint4 vb = *(const uint4*)((const char*)xsrc + ((size_t)sb << 8) + sl * 16);
        acc[0] += bflo(va.x); acc[1] += __uint_as_float(va.x);   // hi unmasked:
        acc[2] += bflo(va.y); acc[3] += __uint_as_float(va.y);   // <=2^-9 rel noise
        acc[4] += bflo(va.z); acc[5] += __uint_as_float(va.z);
        acc[6] += bflo(va.w); acc[7] += __uint_as_float(va.w);
        acc[0] += bflo(vb.x); acc[1] += __uint_as_float(vb.x);
        acc[2] += bflo(vb.y); acc[3] += __uint_as_float(vb.y);
        acc[4] += bflo(vb.z); acc[5] += __uint_as_float(vb.z);
        acc[6] += bflo(vb.w); acc[7] += __uint_as_float(vb.w);
    }
    if (j < s1) {
        int s = csr[j];
        uint4 v = *(const uint4*)((const char*)xsrc + ((size_t)s << 8) + sl * 16);
        acc[0] += bflo(v.x); acc[1] += __uint_as_float(v.x);
        acc[2] += bflo(v.y); acc[3] += __uint_as_float(v.y);
        acc[4] += bflo(v.z); acc[5] += __uint_as_float(v.z);
        acc[6] += bflo(v.w); acc[7] += __uint_as_float(v.w);
    }

#pragma unroll
    for (int i = 0; i < 8; ++i) {
        acc[i] += __shfl_xor(acc[i], 16);
        acc[i] += __shfl_xor(acc[i], 32);
    }
    if (sub == 0) {
        uint4v o;
        o.x = f2bf(acc[0]) | ((unsigned)f2bf(acc[1]) << 16);
        o.y = f2bf(acc[2]) | ((unsigned)f2bf(acc[3]) << 16);
        o.z = f2bf(acc[4]) | ((unsigned)f2bf(acc[5]) << 16);
        o.w = f2bf(acc[6]) | ((unsigned)f2bf(acc[7]) << 16);
        __builtin_nontemporal_store(
            o, (uint4v*)((char*)agg + ((size_t)d << 8) + sl * 16));
    }
}

// ---------------------------------------------------------------------------
// MFMA node update, column-split (unchanged — verified win)
// ---------------------------------------------------------------------------
__global__ __launch_bounds__(256) void linear_mfma_duo(
        const unsigned short* __restrict__ xsA, const unsigned short* __restrict__ xmA,
        const unsigned short* __restrict__ BpA, const float* __restrict__ bsA,
        const float* __restrict__ bmA, const int* __restrict__ degA_, int nA,
        unsigned short* __restrict__ outA, int gmA,
        const unsigned short* __restrict__ xsP, const unsigned short* __restrict__ xmP,
        const unsigned short* __restrict__ BpP, const float* __restrict__ bsP,
        const float* __restrict__ bmP, const int* __restrict__ degP_, int nP,
        unsigned short* __restrict__ outP, int relu) {
    __shared__ uint4 lds4[2048];   // 32 KB: [64][256] bf16 swizzled
    unsigned char* lds = (unsigned char*)lds4;
    int tid = threadIdx.x;
    int wave = tid >> 6, lane = tid & 63;

    const unsigned short *xs, *xm, *Bpack; const float *bs, *bm;
    const int* deg; int n; unsigned short* out;
    int b = blockIdx.x;
    if (b < gmA) { xs = xsA; xm = xmA; Bpack = BpA; bs = bsA; bm = bmA;
                   deg = degA_; n = nA; out = outA; }
    else { b -= gmA; xs = xsP; xm = xmP; Bpack = BpP; bs = bsP; bm = bmP;
           deg = degP_; n = nP; out = outP; }
    int r_base = b * 64;

    // ---- load this wave's B slice (cols 32w..32w+31): 16 fragments, once ----
    const bf16x8_t* bp = (const bf16x8_t*)Bpack;
    bf16x8_t bb[2][8];
#pragma unroll
    for (int nf2 = 0; nf2 < 2; ++nf2)
#pragma unroll
        for (int ks = 0; ks < 8; ++ks)
            bb[nf2][ks] = bp[((wave * 2 + nf2) * 8 + ks) * 64 + lane];

    // ---- stage [xs|xm] tile: 2048 16B chunks, 8 per thread ----
#pragma unroll
    for (int i = 0; i < 8; ++i) {
        int c = i * 256 + tid;        // 0..2047
        int row = c >> 5;             // 0..63
        int kc = (c & 31) * 8;        // bf16 elem offset 0..248
        int rg = r_base + row;
        uint4 w = make_uint4(0, 0, 0, 0);
        if (rg < n) {
            const unsigned short* src = (kc < D) ? (xs + (size_t)rg * D + kc)
                                                 : (xm + (size_t)rg * D + (kc - D));
            w = *(const uint4*)src;
        }
        unsigned addr = ((unsigned)(row * 512 + kc * 2)) ^ ((unsigned)((row & 7) << 4));
        *(uint4*)(lds + addr) = w;
    }
    __syncthreads();

    // ---- row sub-tile loop: a from LDS, 16 MFMAs per rt ----
    f32x4_t acc[4][2];
#pragma unroll
    for (int rt = 0; rt < 4; ++rt)
#pragma unroll
        for (int nf2 = 0; nf2 < 2; ++nf2) acc[rt][nf2] = (f32x4_t){0.f, 0.f, 0.f, 0.f};

#pragma unroll
    for (int rt = 0; rt < 4; ++rt) {
        int lrow = rt * 16 + (lane & 15);
        bf16x8_t a[8];
#pragma unroll
        for (int ks = 0; ks < 8; ++ks) {
            unsigned addr = ((unsigned)(lrow * 512 + ks * 64 + (lane >> 4) * 16))
                            ^ ((unsigned)((lrow & 7) << 4));
            a[ks] = *(const bf16x8_t*)(lds + addr);
        }
#pragma unroll
        for (int ks = 0; ks < 8; ++ks) {
            acc[rt][0] = __builtin_amdgcn_mfma_f32_16x16x32_bf16(a[ks], bb[0][ks], acc[rt][0], 0, 0, 0);
            acc[rt][1] = __builtin_amdgcn_mfma_f32_16x16x32_bf16(a[ks], bb[1][ks], acc[rt][1], 0, 0, 0);
        }
    }

    // ---- epilogue: wave w writes cols [32w,32w+32) for all 64 rows ----
#pragma unroll
    for (int nf2 = 0; nf2 < 2; ++nf2) {
        int col = wave * 32 + nf2 * 16 + (lane & 15);
        float bsv = bs[col], bmv = bm[col];
#pragma unroll
        for (int rt = 0; rt < 4; ++rt) {
            int rb2 = r_base + rt * 16 + (lane >> 4) * 4;
#pragma unroll
            for (int rr = 0; rr < 4; ++rr) {
                int r = rb2 + rr;
                if (r < n) {
                    float dgv = (float)deg[r];
                    float v = acc[rt][nf2][rr] + bsv + dgv * bmv;
                    if (relu) v = fmaxf(v, 0.f);
                    out[(size_t)r * D + col] = f2bf(v);
                }
            }
        }
    }
}

// ---------------------------------------------------------------------------
// supervision dot products on bf16 embeddings
// ---------------------------------------------------------------------------
__global__ __launch_bounds__(256) void dot_kernel(
        const unsigned short* __restrict__ za, const unsigned short* __restrict__ zp,
        const int* __restrict__ sa, const int* __restrict__ sp, int S,
        float* __restrict__ out) {
    int gw   = (blockIdx.x * 256 + threadIdx.x) >> 6;
    int lane = threadIdx.x & 63;
    int nw   = (gridDim.x * 256) >> 6;
    for (int i = gw; i < S; i += nw) {
        int a = sa[i], p = sp[i];
        unsigned ua = *(const unsigned*)(za + (size_t)a * D + lane * 2);
        unsigned up = *(const unsigned*)(zp + (size_t)p * D + lane * 2);
        float s = bflo(ua) * bflo(up)
                + __uint_as_float(ua & 0xffff0000u) * __uint_as_float(up & 0xffff0000u);
#pragma unroll
        for (int off = 32; off > 0; off >>= 1) s += __shfl_xor(s, off);
        if (lane == 0) out[i] = s;
    }
}

// ---------------------------------------------------------------------------
extern "C" void kernel_launch(void* const* d_in, const int* in_sizes, int n_in,
                              void* d_out, int out_size, void* d_ws, size_t ws_size,
                              hipStream_t stream) {
    const float* x_a  = (const float*)d_in[0];
    const float* x_p  = (const float*)d_in[1];
    const int*   ea   = (const int*)d_in[2];
    const int*   ep   = (const int*)d_in[3];
    const int*   sa   = (const int*)d_in[4];
    const int*   sp   = (const int*)d_in[5];
    const float* WsA  = (const float*)d_in[6];
    const float* bsA  = (const float*)d_in[7];
    const float* WsP  = (const float*)d_in[8];
    const float* bsP  = (const float*)d_in[9];
    const float* Wa2p = (const float*)d_in[10];
    const float* ba2p = (const float*)d_in[11];
    const float* Wp2a = (const float*)d_in[12];
    const float* bp2a = (const float*)d_in[13];

    const int nA = in_sizes[0] / D;   // 100000
    const int nP = in_sizes[1] / D;   // 200000
    const int E  = in_sizes[2];       // 600000
    const int S  = in_sizes[4];       // 100000

    // ---- workspace layout ----
    char* ws = (char*)d_ws;
    size_t curoff = 0;
    auto alloc = [&](size_t bytes) -> void* {
        void* p = ws + curoff;
        curoff = (curoff + bytes + 255) & ~(size_t)255;
        return p;
    };
    unsigned short* xb_a  = (unsigned short*)alloc((size_t)nA * D * 2);
    unsigned short* xb_p  = (unsigned short*)alloc((size_t)nP * D * 2);
    unsigned short* agg_a = (unsigned short*)alloc((size_t)nA * D * 2);
    unsigned short* agg_p = (unsigned short*)alloc((size_t)nP * D * 2);
    unsigned short* y_a   = (unsigned short*)alloc((size_t)nA * D * 2);
    unsigned short* y_p   = (unsigned short*)alloc((size_t)nP * D * 2);
    unsigned short* z_a   = (unsigned short*)alloc((size_t)nA * D * 2);
    unsigned short* z_p   = (unsigned short*)alloc((size_t)nP * D * 2);
    int* degA = (int*)alloc((size_t)nA * 4);
    int* degP = (int*)alloc((size_t)nP * 4);
    int* rsA  = (int*)alloc(((size_t)nA + 1) * 4);
    int* rsP  = (int*)alloc(((size_t)nP + 1) * 4);
    int* csrA = (int*)alloc((size_t)E * 4);
    int* csrP = (int*)alloc((size_t)E * 4);
    unsigned short* Bpack = (unsigned short*)alloc((size_t)4 * 32768 * 2);  // 256 KB

    // preprocessing scratch aliases z_a/z_p (done before layer-1 writes z)
    const int nbcA = (nA + CB_NODES - 1) >> CB_SHIFT;   // 98
    const int nbcP = (nP + CB_NODES - 1) >> CB_SHIFT;   // 196
    const int NBC  = nbcA + nbcP;                       // 294
    unsigned* buf = (unsigned*)z_a;           // 2E*4 = 4.8 MB
    int* gcur  = (int*)z_p;                   // NBC_MAX ints
    int* cbase = gcur + NBC_MAX;
    int* chist = cbase + NBC_MAX;

    const int nchunk = (E + CHE - 1) / CHE;   // 293

    // ---- bf16 input copies + graph preprocessing + W packing ----
    f32_to_bf16_duo<<<3072, 256, 0, stream>>>(x_a, xb_a, nA * D / 8,
                                              x_p, xb_p, nP * D / 8);
    hipMemsetAsync(chist, 0, NBC_MAX * 4, stream);
    pack_w_kernel<<<64, 256, 0, stream>>>(WsA, WsP, Wa2p, Wp2a, Bpack);
    coarse_count_kernel<<<nchunk, 256, 0, stream>>>(ea, ep, E, nbcA, NBC, chist);
    coarse_scan_kernel<<<1, NBC_MAX, 0, stream>>>(chist, nbcA, NBC, E,
                                                  gcur, cbase, rsA + nA, rsP + nP);
    multisplit_kernel<<<nchunk, 512, 0, stream>>>(ea, ep, E, nbcA, gcur, buf);
    fine_csr_kernel<<<NBC, 1024, 0, stream>>>(buf, E, nbcA, cbase, chist,
                                              rsA, degA, csrA, nA,
                                              rsP, degP, csrP, nP);

    const int gmA = (nA + 63) / 64;   // 1563
    const int gmP = (nP + 63) / 64;   // 3125
    const int gAgg = (nA + nP + 3) / 4;

    // ---- layer 0 (relu) ----
    aggregate_duo<<<gAgg, 256, 0, stream>>>(xb_p, rsA, csrA, nA, agg_a,
                                            xb_a, rsP, csrP, nP, agg_p);
    linear_mfma_duo<<<gmA + gmP, 256, 0, stream>>>(
        xb_a, agg_a, Bpack + 0 * 32768, bsA, bp2a, degA, nA, y_a, gmA,
        xb_p, agg_p, Bpack + 1 * 32768, bsP, ba2p, degP, nP, y_p, 1);

    // ---- layer 1 (no relu) ----
    aggregate_duo<<<gAgg, 256, 0, stream>>>(y_p, rsA, csrA, nA, agg_a,
                                            y_a, rsP, csrP, nP, agg_p);
    linear_mfma_duo<<<gmA + gmP, 256, 0, stream>>>(
        y_a, agg_a, Bpack + 2 * 32768, bsA + D, bp2a + D, degA, nA, z_a, gmA,
        y_p, agg_p, Bpack + 3 * 32768, bsP + D, ba2p + D, degP, nP, z_p, 0);

    // ---- supervision scores ----
    dot_kernel<<<(S + 3) / 4, 256, 0, stream>>>(z_a, z_p, sa, sp, S, (float*)d_out);
}

// Round 16
// 421.971 us; speedup vs baseline: 1.0950x; 1.0950x over previous
//
#include <hip/hip_runtime.h>
#include <stdint.h>

#define D 128
#define CB_SHIFT 10     // coarse bucket = 1024 dst nodes
#define CB_NODES 1024
#define CHE 2048        // edges per multisplit chunk (2*CHE entries)
#define NBC_MAX 512

typedef __attribute__((ext_vector_type(8))) short bf16x8_t;
typedef __attribute__((ext_vector_type(4))) float f32x4_t;

__device__ inline unsigned short f2bf(float x) {
    unsigned int u = __float_as_uint(x);
    unsigned int r = (u + 0x7fffu + ((u >> 16) & 1u)) >> 16;   // RNE
    return (unsigned short)r;
}
__device__ inline float bflo(unsigned v) { return __uint_as_float(v << 16); }

// ---------------------------------------------------------------------------
// f32 -> bf16 bulk convert, both arrays in one launch
// ---------------------------------------------------------------------------
__global__ __launch_bounds__(256) void f32_to_bf16_duo(
        const float* __restrict__ inA, unsigned short* __restrict__ outA, int n8A,
        const float* __restrict__ inP, unsigned short* __restrict__ outP, int n8P) {
    int stride = gridDim.x * blockDim.x;
    int total = n8A + n8P;
    for (int i = blockIdx.x * blockDim.x + threadIdx.x; i < total; i += stride) {
        const float* in; unsigned short* out; int j;
        if (i < n8A) { in = inA; out = outA; j = i; }
        else         { in = inP; out = outP; j = i - n8A; }
        float4 v0 = *(const float4*)(in + (size_t)j * 8);
        float4 v1 = *(const float4*)(in + (size_t)j * 8 + 4);
        uint4 o;
        o.x = f2bf(v0.x) | ((unsigned)f2bf(v0.y) << 16);
        o.y = f2bf(v0.z) | ((unsigned)f2bf(v0.w) << 16);
        o.z = f2bf(v1.x) | ((unsigned)f2bf(v1.y) << 16);
        o.w = f2bf(v1.z) | ((unsigned)f2bf(v1.w) << 16);
        *(uint4*)(out + (size_t)j * 8) = o;
    }
}

// ---------------------------------------------------------------------------
// coarse bucket histogram
// ---------------------------------------------------------------------------
__global__ __launch_bounds__(256) void coarse_count_kernel(
        const int* __restrict__ ea, const int* __restrict__ ep, int E,
        int nbcA, int nbc, int* __restrict__ chist) {
    __shared__ int hist[NBC_MAX];
    int tid = threadIdx.x;
    for (int i = tid; i < NBC_MAX; i += 256) hist[i] = 0;
    __syncthreads();
    int e0 = blockIdx.x * CHE;
    int ecnt = E - e0; if (ecnt > CHE) ecnt = CHE;
    for (int k = tid; k < ecnt; k += 256) {
        int a = ea[e0 + k], p = ep[e0 + k];
        atomicAdd(&hist[a >> CB_SHIFT], 1);
        atomicAdd(&hist[nbcA + (p >> CB_SHIFT)], 1);
    }
    __syncthreads();
    for (int i = tid; i < nbc; i += 256)
        if (hist[i]) atomicAdd(&chist[i], hist[i]);
}

// ---------------------------------------------------------------------------
// tiny segmented scan of the coarse counts (1 block)
// ---------------------------------------------------------------------------
__global__ __launch_bounds__(NBC_MAX) void coarse_scan_kernel(
        const int* __restrict__ chist, int nbcA, int nbc, int E,
        int* __restrict__ gcur, int* __restrict__ cbase,
        int* __restrict__ rsA_end, int* __restrict__ rsP_end) {
    __shared__ int s[NBC_MAX];
    int tid = threadIdx.x;
    int v = (tid < nbc) ? chist[tid] : 0;
    s[tid] = v;
    __syncthreads();
    for (int off = 1; off < NBC_MAX; off <<= 1) {
        int add = 0;
        if (tid >= off && ((tid < nbcA) || (tid - off >= nbcA))) add = s[tid - off];
        __syncthreads();
        s[tid] += add;
        __syncthreads();
    }
    int excl = s[tid] - v;
    if (tid < nbc) {
        cbase[tid] = excl;
        gcur[tid] = (tid < nbcA) ? excl : E + excl;
    }
    if (tid == 0) { *rsA_end = E; *rsP_end = E; }
}

// ---------------------------------------------------------------------------
// LDS multisplit (block-owned contiguous runs per coarse bucket), 512 thr
// ---------------------------------------------------------------------------
__global__ __launch_bounds__(512) void multisplit_kernel(
        const int* __restrict__ ea, const int* __restrict__ ep, int E,
        int nbcA, int* __restrict__ gcur, unsigned* __restrict__ buf) {
    __shared__ int hist[NBC_MAX];
    __shared__ int off[NBC_MAX];
    __shared__ int cnt2[NBC_MAX];
    __shared__ int gbase[NBC_MAX];
    __shared__ unsigned cbuf[2 * CHE];          // 16 KB
    __shared__ unsigned short bkt[2 * CHE];     // 8 KB

    int tid = threadIdx.x;
    int e0 = blockIdx.x * CHE;
    int ecnt = E - e0; if (ecnt > CHE) ecnt = CHE;

    hist[tid] = 0;
    __syncthreads();

    for (int k = tid; k < ecnt; k += 512) {
        int a = ea[e0 + k], p = ep[e0 + k];
        atomicAdd(&hist[a >> CB_SHIFT], 1);
        atomicAdd(&hist[nbcA + (p >> CB_SHIFT)], 1);
    }
    __syncthreads();

    int v = hist[tid];
    off[tid] = v;
    __syncthreads();
    for (int o = 1; o < NBC_MAX; o <<= 1) {
        int y = (tid >= o) ? off[tid - o] : 0;
        __syncthreads();
        off[tid] += y;
        __syncthreads();
    }
    int excl = off[tid] - v;
    off[tid] = excl;
    cnt2[tid] = 0;
    if (v > 0) gbase[tid] = atomicAdd(&gcur[tid], v);
    __syncthreads();

    for (int k = tid; k < ecnt; k += 512) {
        int a = ea[e0 + k], p = ep[e0 + k];
        int bA = a >> CB_SHIFT;
        int iA = off[bA] + atomicAdd(&cnt2[bA], 1);
        cbuf[iA] = ((unsigned)p << CB_SHIFT) | (unsigned)(a & (CB_NODES - 1));
        bkt[iA] = (unsigned short)bA;
        int bP = nbcA + (p >> CB_SHIFT);
        int iP = off[bP] + atomicAdd(&cnt2[bP], 1);
        cbuf[iP] = ((unsigned)a << CB_SHIFT) | (unsigned)(p & (CB_NODES - 1));
        bkt[iP] = (unsigned short)bP;
    }
    __syncthreads();

    int total = 2 * ecnt;
    for (int i = tid; i < total; i += 512) {
        int b = bkt[i];
        buf[(size_t)gbase[b] + (i - off[b])] = cbuf[i];
    }
}

// ---------------------------------------------------------------------------
// fine sort + LOCAL deg/rs derivation: one block per coarse bucket.
// ---------------------------------------------------------------------------
__global__ __launch_bounds__(1024) void fine_csr_kernel(
        const unsigned* __restrict__ buf, int E, int nbcA,
        const int* __restrict__ cbase, const int* __restrict__ chist,
        int* __restrict__ rsA, int* __restrict__ degA, int* __restrict__ csrA, int nA,
        int* __restrict__ rsP, int* __restrict__ degP, int* __restrict__ csrP, int nP) {
    __shared__ int cnt[CB_NODES];
    __shared__ int s[CB_NODES];
    __shared__ int pos[CB_NODES];
    int b = blockIdx.x;
    int tid = threadIdx.x;
    int isA = (b < nbcA);
    int d0 = (isA ? b : b - nbcA) << CB_SHIFT;
    int n  = isA ? nA : nP;
    int* rs  = isA ? rsA  : rsP;
    int* deg = isA ? degA : degP;
    int* csr = isA ? csrA : csrP;
    int cb   = cbase[b];
    int cntE = chist[b];
    size_t bstart = (isA ? (size_t)0 : (size_t)E) + (size_t)cb;

    cnt[tid] = 0;
    __syncthreads();
    for (int j = tid; j < cntE; j += 1024)
        atomicAdd(&cnt[buf[bstart + j] & (CB_NODES - 1)], 1);
    __syncthreads();

    int v = cnt[tid];
    s[tid] = v;
    __syncthreads();
    for (int o = 1; o < CB_NODES; o <<= 1) {
        int y = (tid >= o) ? s[tid - o] : 0;
        __syncthreads();
        s[tid] += y;
        __syncthreads();
    }
    int excl = s[tid] - v;
    int d = d0 + tid;
    if (d < n) { rs[d] = cb + excl; deg[d] = v; }

    pos[tid] = 0;
    cnt[tid] = excl;   // repurpose: per-dst exclusive base
    __syncthreads();

    for (int j = tid; j < cntE; j += 1024) {
        unsigned pk = buf[bstart + j];
        int li = pk & (CB_NODES - 1);
        int src = (int)(pk >> CB_SHIFT);
        int p = cb + cnt[li] + atomicAdd(&pos[li], 1);
        csr[p] = src;
    }
}

// ---------------------------------------------------------------------------
// W pre-pack (unchanged)
// ---------------------------------------------------------------------------
__global__ __launch_bounds__(256) void pack_w_kernel(
        const float* __restrict__ WsA, const float* __restrict__ WsP,
        const float* __restrict__ Wa2p, const float* __restrict__ Wp2a,
        unsigned short* __restrict__ Bpack) {
    int combo = blockIdx.x >> 4;
    int e = (blockIdx.x & 15) * 256 + threadIdx.x;   // 0..4095
    int layer = combo >> 1;
    const float* Ws = ((combo & 1) ? WsP : WsA) + (size_t)layer * D * D;
    const float* Wm = ((combo & 1) ? Wa2p : Wp2a) + (size_t)layer * D * D;

    int f = e >> 6, lane = e & 63;
    int nf = f >> 3, ks = f & 7;
    int k0 = ks * 32 + (lane >> 4) * 8;
    int col = nf * 16 + (lane & 15);

    unsigned short v[8];
#pragma unroll
    for (int j = 0; j < 8; ++j) {
        int k = k0 + j;
        float x = (k < D) ? Ws[(size_t)k * D + col] : Wm[(size_t)(k - D) * D + col];
        v[j] = f2bf(x);
    }
    uint4 o;
    o.x = v[0] | ((unsigned)v[1] << 16);
    o.y = v[2] | ((unsigned)v[3] << 16);
    o.z = v[4] | ((unsigned)v[5] << 16);
    o.w = v[6] | ((unsigned)v[7] << 16);
    *(uint4*)(Bpack + (size_t)combo * 32768 + (size_t)e * 8) = o;
}

// ---------------------------------------------------------------------------
// bf16 pull-aggregation: one wave per dst row, 4x16-lane subwaves, 16B/lane,
// dual-chain unroll with direct csr loads. PLAIN stores (round-15 nt-store
// experiment regressed: it evicted agg from L3 and starved the linear).
// This kernel is at the random-gather concurrency floor (4 structural
// experiments all null): ~95us/dispatch.
// ---------------------------------------------------------------------------
__global__ __launch_bounds__(256) void aggregate_duo(
        const unsigned short* __restrict__ srcA, const int* __restrict__ rsA,
        const int* __restrict__ csrA, int nA, unsigned short* __restrict__ aggA,
        const unsigned short* __restrict__ srcP, const int* __restrict__ rsP,
        const int* __restrict__ csrP, int nP, unsigned short* __restrict__ aggP) {
    int gw   = (blockIdx.x * 256 + threadIdx.x) >> 6;
    int lane = threadIdx.x & 63;
    int sub  = lane >> 4;
    int sl   = lane & 15;

    const unsigned short* xsrc; const int* rs; const int* csr;
    unsigned short* agg; int d;
    if (gw < nA) { d = gw;      xsrc = srcA; rs = rsA; csr = csrA; agg = aggA; }
    else {
        d = gw - nA;
        if (d >= nP) return;
        xsrc = srcP; rs = rsP; csr = csrP; agg = aggP;
    }

    int s0 = rs[d], s1 = rs[d + 1];
    float acc[8] = {0.f, 0.f, 0.f, 0.f, 0.f, 0.f, 0.f, 0.f};
    int j = s0 + sub;
    for (; j + 4 < s1; j += 8) {
        int sa = csr[j];
        int sb = csr[j + 4];
        uint4 va = *(const uint4*)((const char*)xsrc + ((size_t)sa << 8) + sl * 16);
        uint4 vb = *(const uint4*)((const char*)xsrc + ((size_t)sb << 8) + sl * 16);
        acc[0] += bflo(va.x); acc[1] += __uint_as_float(va.x);   // hi unmasked:
        acc[2] += bflo(va.y); acc[3] += __uint_as_float(va.y);   // <=2^-9 rel noise
        acc[4] += bflo(va.z); acc[5] += __uint_as_float(va.z);
        acc[6] += bflo(va.w); acc[7] += __uint_as_float(va.w);
        acc[0] += bflo(vb.x); acc[1] += __uint_as_float(vb.x);
        acc[2] += bflo(vb.y); acc[3] += __uint_as_float(vb.y);
        acc[4] += bflo(vb.z); acc[5] += __uint_as_float(vb.z);
        acc[6] += bflo(vb.w); acc[7] += __uint_as_float(vb.w);
    }
    if (j < s1) {
        int s = csr[j];
        uint4 v = *(const uint4*)((const char*)xsrc + ((size_t)s << 8) + sl * 16);
        acc[0] += bflo(v.x); acc[1] += __uint_as_float(v.x);
        acc[2] += bflo(v.y); acc[3] += __uint_as_float(v.y);
        acc[4] += bflo(v.z); acc[5] += __uint_as_float(v.z);
        acc[6] += bflo(v.w); acc[7] += __uint_as_float(v.w);
    }

#pragma unroll
    for (int i = 0; i < 8; ++i) {
        acc[i] += __shfl_xor(acc[i], 16);
        acc[i] += __shfl_xor(acc[i], 32);
    }
    if (sub == 0) {
        uint4 o;
        o.x = f2bf(acc[0]) | ((unsigned)f2bf(acc[1]) << 16);
        o.y = f2bf(acc[2]) | ((unsigned)f2bf(acc[3]) << 16);
        o.z = f2bf(acc[4]) | ((unsigned)f2bf(acc[5]) << 16);
        o.w = f2bf(acc[6]) | ((unsigned)f2bf(acc[7]) << 16);
        *(uint4*)((char*)agg + ((size_t)d << 8) + sl * 16) = o;
    }
}

// ---------------------------------------------------------------------------
// MFMA node update, column-split, with LDS-STAGED EPILOGUE:
// the old epilogue's 2-byte scattered stores caused 1.2x write amplification
// (round-15 counters: WRITE 91.9MB vs 76.8 logical). Now: bias+deg+relu ->
// bf16 into LDS [64][128] (input tile is dead after the MFMAs), barrier,
// fully-coalesced uint4 streaming stores (1KB/wave/instr).
// ---------------------------------------------------------------------------
__global__ __launch_bounds__(256) void linear_mfma_duo(
        const unsigned short* __restrict__ xsA, const unsigned short* __restrict__ xmA,
        const unsigned short* __restrict__ BpA, const float* __restrict__ bsA,
        const float* __restrict__ bmA, const int* __restrict__ degA_, int nA,
        unsigned short* __restrict__ outA, int gmA,
        const unsigned short* __restrict__ xsP, const unsigned short* __restrict__ xmP,
        const unsigned short* __restrict__ BpP, const float* __restrict__ bsP,
        const float* __restrict__ bmP, const int* __restrict__ degP_, int nP,
        unsigned short* __restrict__ outP, int relu) {
    __shared__ uint4 lds4[2048];   // 32 KB: input tile, then output tile
    unsigned char* lds = (unsigned char*)lds4;
    int tid = threadIdx.x;
    int wave = tid >> 6, lane = tid & 63;

    const unsigned short *xs, *xm, *Bpack; const float *bs, *bm;
    const int* deg; int n; unsigned short* out;
    int b = blockIdx.x;
    if (b < gmA) { xs = xsA; xm = xmA; Bpack = BpA; bs = bsA; bm = bmA;
                   deg = degA_; n = nA; out = outA; }
    else { b -= gmA; xs = xsP; xm = xmP; Bpack = BpP; bs = bsP; bm = bmP;
           deg = degP_; n = nP; out = outP; }
    int r_base = b * 64;

    // ---- load this wave's B slice (cols 32w..32w+31): 16 fragments, once ----
    const bf16x8_t* bp = (const bf16x8_t*)Bpack;
    bf16x8_t bb[2][8];
#pragma unroll
    for (int nf2 = 0; nf2 < 2; ++nf2)
#pragma unroll
        for (int ks = 0; ks < 8; ++ks)
            bb[nf2][ks] = bp[((wave * 2 + nf2) * 8 + ks) * 64 + lane];

    // ---- stage [xs|xm] tile: 2048 16B chunks, 8 per thread ----
#pragma unroll
    for (int i = 0; i < 8; ++i) {
        int c = i * 256 + tid;        // 0..2047
        int row = c >> 5;             // 0..63
        int kc = (c & 31) * 8;        // bf16 elem offset 0..248
        int rg = r_base + row;
        uint4 w = make_uint4(0, 0, 0, 0);
        if (rg < n) {
            const unsigned short* src = (kc < D) ? (xs + (size_t)rg * D + kc)
                                                 : (xm + (size_t)rg * D + (kc - D));
            w = *(const uint4*)src;
        }
        unsigned addr = ((unsigned)(row * 512 + kc * 2)) ^ ((unsigned)((row & 7) << 4));
        *(uint4*)(lds + addr) = w;
    }
    __syncthreads();

    // ---- row sub-tile loop: a from LDS, 16 MFMAs per rt ----
    f32x4_t acc[4][2];
#pragma unroll
    for (int rt = 0; rt < 4; ++rt)
#pragma unroll
        for (int nf2 = 0; nf2 < 2; ++nf2) acc[rt][nf2] = (f32x4_t){0.f, 0.f, 0.f, 0.f};

#pragma unroll
    for (int rt = 0; rt < 4; ++rt) {
        int lrow = rt * 16 + (lane & 15);
        bf16x8_t a[8];
#pragma unroll
        for (int ks = 0; ks < 8; ++ks) {
            unsigned addr = ((unsigned)(lrow * 512 + ks * 64 + (lane >> 4) * 16))
                            ^ ((unsigned)((lrow & 7) << 4));
            a[ks] = *(const bf16x8_t*)(lds + addr);
        }
#pragma unroll
        for (int ks = 0; ks < 8; ++ks) {
            acc[rt][0] = __builtin_amdgcn_mfma_f32_16x16x32_bf16(a[ks], bb[0][ks], acc[rt][0], 0, 0, 0);
            acc[rt][1] = __builtin_amdgcn_mfma_f32_16x16x32_bf16(a[ks], bb[1][ks], acc[rt][1], 0, 0, 0);
        }
    }

    // ---- epilogue: bias + deg*bm + relu -> LDS bf16 [64][128] ----
    __syncthreads();   // all waves done reading the input tile
    unsigned short* lout = (unsigned short*)lds;
    int sl = lane & 15;
#pragma unroll
    for (int nf2 = 0; nf2 < 2; ++nf2) {
        int col = wave * 32 + nf2 * 16 + sl;
        float bsv = bs[col], bmv = bm[col];
#pragma unroll
        for (int rt = 0; rt < 4; ++rt) {
            int row0 = rt * 16 + (lane >> 4) * 4;
#pragma unroll
            for (int rr = 0; rr < 4; ++rr) {
                int row = row0 + rr;
                int r = r_base + row;
                float dgv = (r < n) ? (float)deg[r] : 0.f;
                float v = acc[rt][nf2][rr] + bsv + dgv * bmv;
                if (relu) v = fmaxf(v, 0.f);
                lout[row * 128 + col] = f2bf(v);
            }
        }
    }
    __syncthreads();

    // ---- coalesced streaming stores: 1024 x 16B chunks, 4 per thread ----
#pragma unroll
    for (int i = 0; i < 4; ++i) {
        int c = i * 256 + tid;        // 0..1023
        int row = c >> 4;             // 16 chunks per 256B row
        int kc = (c & 15) * 8;
        int rg = r_base + row;
        if (rg < n)
            *(uint4*)(out + (size_t)rg * D + kc) = *(const uint4*)(lout + row * 128 + kc);
    }
}

// ---------------------------------------------------------------------------
// supervision dot products on bf16 embeddings
// ---------------------------------------------------------------------------
__global__ __launch_bounds__(256) void dot_kernel(
        const unsigned short* __restrict__ za, const unsigned short* __restrict__ zp,
        const int* __restrict__ sa, const int* __restrict__ sp, int S,
        float* __restrict__ out) {
    int gw   = (blockIdx.x * 256 + threadIdx.x) >> 6;
    int lane = threadIdx.x & 63;
    int nw   = (gridDim.x * 256) >> 6;
    for (int i = gw; i < S; i += nw) {
        int a = sa[i], p = sp[i];
        unsigned ua = *(const unsigned*)(za + (size_t)a * D + lane * 2);
        unsigned up = *(const unsigned*)(zp + (size_t)p * D + lane * 2);
        float s = bflo(ua) * bflo(up)
                + __uint_as_float(ua & 0xffff0000u) * __uint_as_float(up & 0xffff0000u);
#pragma unroll
        for (int off = 32; off > 0; off >>= 1) s += __shfl_xor(s, off);
        if (lane == 0) out[i] = s;
    }
}

// ---------------------------------------------------------------------------
extern "C" void kernel_launch(void* const* d_in, const int* in_sizes, int n_in,
                              void* d_out, int out_size, void* d_ws, size_t ws_size,
                              hipStream_t stream) {
    const float* x_a  = (const float*)d_in[0];
    const float* x_p  = (const float*)d_in[1];
    const int*   ea   = (const int*)d_in[2];
    const int*   ep   = (const int*)d_in[3];
    const int*   sa   = (const int*)d_in[4];
    const int*   sp   = (const int*)d_in[5];
    const float* WsA  = (const float*)d_in[6];
    const float* bsA  = (const float*)d_in[7];
    const float* WsP  = (const float*)d_in[8];
    const float* bsP  = (const float*)d_in[9];
    const float* Wa2p = (const float*)d_in[10];
    const float* ba2p = (const float*)d_in[11];
    const float* Wp2a = (const float*)d_in[12];
    const float* bp2a = (const float*)d_in[13];

    const int nA = in_sizes[0] / D;   // 100000
    const int nP = in_sizes[1] / D;   // 200000
    const int E  = in_sizes[2];       // 600000
    const int S  = in_sizes[4];       // 100000

    // ---- workspace layout ----
    char* ws = (char*)d_ws;
    size_t curoff = 0;
    auto alloc = [&](size_t bytes) -> void* {
        void* p = ws + curoff;
        curoff = (curoff + bytes + 255) & ~(size_t)255;
        return p;
    };
    unsigned short* xb_a  = (unsigned short*)alloc((size_t)nA * D * 2);
    unsigned short* xb_p  = (unsigned short*)alloc((size_t)nP * D * 2);
    unsigned short* agg_a = (unsigned short*)alloc((size_t)nA * D * 2);
    unsigned short* agg_p = (unsigned short*)alloc((size_t)nP * D * 2);
    unsigned short* y_a   = (unsigned short*)alloc((size_t)nA * D * 2);
    unsigned short* y_p   = (unsigned short*)alloc((size_t)nP * D * 2);
    unsigned short* z_a   = (unsigned short*)alloc((size_t)nA * D * 2);
    unsigned short* z_p   = (unsigned short*)alloc((size_t)nP * D * 2);
    int* degA = (int*)alloc((size_t)nA * 4);
    int* degP = (int*)alloc((size_t)nP * 4);
    int* rsA  = (int*)alloc(((size_t)nA + 1) * 4);
    int* rsP  = (int*)alloc(((size_t)nP + 1) * 4);
    int* csrA = (int*)alloc((size_t)E * 4);
    int* csrP = (int*)alloc((size_t)E * 4);
    unsigned short* Bpack = (unsigned short*)alloc((size_t)4 * 32768 * 2);  // 256 KB

    // preprocessing scratch aliases z_a/z_p (done before layer-1 writes z)
    const int nbcA = (nA + CB_NODES - 1) >> CB_SHIFT;   // 98
    const int nbcP = (nP + CB_NODES - 1) >> CB_SHIFT;   // 196
    const int NBC  = nbcA + nbcP;                       // 294
    unsigned* buf = (unsigned*)z_a;           // 2E*4 = 4.8 MB
    int* gcur  = (int*)z_p;                   // NBC_MAX ints
    int* cbase = gcur + NBC_MAX;
    int* chist = cbase + NBC_MAX;

    const int nchunk = (E + CHE - 1) / CHE;   // 293

    // ---- bf16 input copies + graph preprocessing + W packing ----
    f32_to_bf16_duo<<<3072, 256, 0, stream>>>(x_a, xb_a, nA * D / 8,
                                              x_p, xb_p, nP * D / 8);
    hipMemsetAsync(chist, 0, NBC_MAX * 4, stream);
    pack_w_kernel<<<64, 256, 0, stream>>>(WsA, WsP, Wa2p, Wp2a, Bpack);
    coarse_count_kernel<<<nchunk, 256, 0, stream>>>(ea, ep, E, nbcA, NBC, chist);
    coarse_scan_kernel<<<1, NBC_MAX, 0, stream>>>(chist, nbcA, NBC, E,
                                                  gcur, cbase, rsA + nA, rsP + nP);
    multisplit_kernel<<<nchunk, 512, 0, stream>>>(ea, ep, E, nbcA, gcur, buf);
    fine_csr_kernel<<<NBC, 1024, 0, stream>>>(buf, E, nbcA, cbase, chist,
                                              rsA, degA, csrA, nA,
                                              rsP, degP, csrP, nP);

    const int gmA = (nA + 63) / 64;   // 1563
    const int gmP = (nP + 63) / 64;   // 3125
    const int gAgg = (nA + nP + 3) / 4;

    // ---- layer 0 (relu) ----
    aggregate_duo<<<gAgg, 256, 0, stream>>>(xb_p, rsA, csrA, nA, agg_a,
                                            xb_a, rsP, csrP, nP, agg_p);
    linear_mfma_duo<<<gmA + gmP, 256, 0, stream>>>(
        xb_a, agg_a, Bpack + 0 * 32768, bsA, bp2a, degA, nA, y_a, gmA,
        xb_p, agg_p, Bpack + 1 * 32768, bsP, ba2p, degP, nP, y_p, 1);

    // ---- layer 1 (no relu) ----
    aggregate_duo<<<gAgg, 256, 0, stream>>>(y_p, rsA, csrA, nA, agg_a,
                                            y_a, rsP, csrP, nP, agg_p);
    linear_mfma_duo<<<gmA + gmP, 256, 0, stream>>>(
        y_a, agg_a, Bpack + 2 * 32768, bsA + D, bp2a + D, degA, nA, z_a, gmA,
        y_p, agg_p, Bpack + 3 * 32768, bsP + D, ba2p + D, degP, nP, z_p, 0);

    // ---- supervision scores ----
    dot_kernel<<<(S + 3) / 4, 256, 0, stream>>>(z_a, z_p, sa, sp, S, (float*)d_out);
}